// Round 2
// baseline (777.596 us; speedup 1.0000x reference)
//
#include <hip/hip_runtime.h>

#define BATCH 16
#define CH 64
#define NPIX 16384   // 128*128
#define TWOC 128

// ---------------------------------------------------------------------------
// Kernel 1: partial Gram matrices G[b][map][64][64] = sum_n V[c,n]*V[d,n]
// map 0 = template (feeds t_attn, used iff omega!=0)
// map 1 = roi      (feeds r_attn, used iff gamma!=0)
// Early-exits when the corresponding scalar is exactly 0 (contribution is
// exactly zero in that case -- algebraic short-circuit, still deterministic).
// ---------------------------------------------------------------------------
__global__ __launch_bounds__(256) void gram_kernel(
    const float* __restrict__ tmap, const float* __restrict__ rmap,
    const float* __restrict__ gamma, const float* __restrict__ omega,
    float* __restrict__ G)
{
    const int map = blockIdx.y;
    const float mult = (map == 0) ? omega[0] : gamma[0];
    if (mult == 0.f) return;   // wave-uniform: skip dead attention branch

    __shared__ float tile[64][68];
    const int chunk = blockIdx.x;    // 0..31 -> 512 cols each
    const int b     = blockIdx.z;
    const float* x = (map == 0 ? tmap : rmap) + (size_t)b * CH * NPIX + chunk * 512;
    const int t  = threadIdx.x;
    const int ti = t >> 4;
    const int tj = t & 15;

    float acc[4][4];
#pragma unroll
    for (int i = 0; i < 4; ++i)
#pragma unroll
        for (int j = 0; j < 4; ++j) acc[i][j] = 0.f;

    for (int tt = 0; tt < 8; ++tt) {
        const int col0 = tt * 64;
#pragma unroll
        for (int k = 0; k < 16; ++k) {
            int e = t + 256 * k;
            int c = e >> 6, col = e & 63;
            tile[c][col] = x[(size_t)c * NPIX + col0 + col];
        }
        __syncthreads();
#pragma unroll 8
        for (int n = 0; n < 64; n += 2) {
            float2 av[4], bv[4];
#pragma unroll
            for (int i = 0; i < 4; ++i) av[i] = *(const float2*)&tile[ti + 16 * i][n];
#pragma unroll
            for (int j = 0; j < 4; ++j) bv[j] = *(const float2*)&tile[tj + 16 * j][n];
#pragma unroll
            for (int i = 0; i < 4; ++i)
#pragma unroll
                for (int j = 0; j < 4; ++j) {
                    acc[i][j] += av[i].x * bv[j].x;
                    acc[i][j] += av[i].y * bv[j].y;
                }
        }
        __syncthreads();
    }
    float* Gp = G + ((size_t)(b * 2 + map) << 12);
#pragma unroll
    for (int i = 0; i < 4; ++i)
#pragma unroll
        for (int j = 0; j < 4; ++j)
            atomicAdd(&Gp[(ti + 16 * i) * 64 + (tj + 16 * j)], acc[i][j]);
}

// ---------------------------------------------------------------------------
// Kernel 2: per-batch softmax + build TRANSPOSED mixing matrix
//   Mt[b][k][o] = conv_w[o][k] + (k<64 ? gamma*(W1@r_attn)[o][k]
//                                       : omega*(W2@t_attn)[o][k-64])
// Attention branches are skipped when their multiplier is exactly 0.
// ---------------------------------------------------------------------------
__global__ __launch_bounds__(128) void finalize_kernel(
    const float* __restrict__ G, const float* __restrict__ gamma,
    const float* __restrict__ omega, const float* __restrict__ conv_w,
    float* __restrict__ Mt)
{
    __shared__ float attn[2][64][64];
    const int b = blockIdx.x;
    const int t = threadIdx.x;
    const float gam = gamma[0], om = omega[0];
    {
        const int map = t >> 6, i = t & 63;
        const float need = (map == 0) ? om : gam;
        if (need != 0.f) {
            const float* Grow = G + ((size_t)(b * 2 + map) << 12) + i * 64;
            float mn = Grow[0];
            for (int j = 1; j < 64; ++j) mn = fminf(mn, Grow[j]);
            float s = 0.f;
            for (int j = 0; j < 64; ++j) s += expf(mn - Grow[j]);
            const float inv = 1.f / s;
            for (int j = 0; j < 64; ++j) attn[map][i][j] = expf(mn - Grow[j]) * inv;
        }
    }
    __syncthreads();
    for (int idx = t; idx < CH * TWOC; idx += 128) {
        const int k = idx >> 6, o = idx & 63;       // Mt layout [128 k][64 o]
        const float* wrow = conv_w + o * TWOC;
        float v;
        if (k < 64) {
            v = wrow[k];
            if (gam != 0.f) {
                float dot = 0.f;
                for (int c = 0; c < 64; ++c) dot += wrow[c] * attn[1][c][k];      // r_attn
                v += gam * dot;
            }
        } else {
            const int d = k - 64;
            v = wrow[k];
            if (om != 0.f) {
                float dot = 0.f;
                for (int c = 0; c < 64; ++c) dot += wrow[64 + c] * attn[0][c][d]; // t_attn
                v += om * dot;
            }
        }
        Mt[(size_t)b * (CH * TWOC) + idx] = v;
    }
}

// ---------------------------------------------------------------------------
// Kernel 3: out[b][o][n] = sum_k Mt[b][k][o] * X[k][n] + conv_b[o]
// X rows 0..63 = template channels, 64..127 = roi channels.
// Block: 256 threads = 4 waves; wave w owns output channels [16w, 16w+16).
// Lane l: li=l>>4 -> channel sub-group (4 ch), lj=l&15 -> 4 px (float4).
// M staged once in LDS [128][64]; X streamed global->reg, 8-deep double
// buffer, no barriers in the main loop.
// grid (64 chunks of 256 px, 16 batches).
// ---------------------------------------------------------------------------
__global__ __launch_bounds__(256) void out_kernel(
    const float* __restrict__ tmap, const float* __restrict__ rmap,
    const float* __restrict__ Mt, const float* __restrict__ conv_b,
    float* __restrict__ out)
{
    __shared__ float Ms[128][64];     // 32 KB, [k][o]
    const int b = blockIdx.y;
    const int t = threadIdx.x;

    // stage Mt[b] -> LDS (straight vector copy)
    {
        const float4* src = (const float4*)(Mt + (size_t)b * (CH * TWOC));
        float4* dst = (float4*)&Ms[0][0];
#pragma unroll
        for (int i = 0; i < 8; ++i) dst[t + 256 * i] = src[t + 256 * i];
    }
    __syncthreads();

    const int w  = t >> 6;
    const int l  = t & 63;
    const int li = l >> 4;
    const int lj = l & 15;
    const int och = w * 16 + li * 4;

    const float4 bias = *(const float4*)&conv_b[och];
    const float* xb_t = tmap + (size_t)b * CH * NPIX;
    const float* xb_r = rmap + (size_t)b * CH * NPIX;

    for (int tile = 0; tile < 4; ++tile) {
        const int px = blockIdx.x * 256 + tile * 64 + lj * 4;

        float4 buf[2][8];
        float acc[4][4];
#pragma unroll
        for (int i = 0; i < 4; ++i)
#pragma unroll
            for (int c = 0; c < 4; ++c) acc[i][c] = 0.f;

#pragma unroll
        for (int j = 0; j < 8; ++j)
            buf[0][j] = *(const float4*)&xb_t[(size_t)j * NPIX + px];

#pragma unroll
        for (int kb = 0; kb < 16; ++kb) {
            if (kb < 15) {
                const int kn = (kb + 1) * 8;
                const float* src = (kn < 64) ? &xb_t[(size_t)kn * NPIX]
                                             : &xb_r[(size_t)(kn - 64) * NPIX];
#pragma unroll
                for (int j = 0; j < 8; ++j)
                    buf[(kb + 1) & 1][j] = *(const float4*)&src[(size_t)j * NPIX + px];
            }
#pragma unroll
            for (int j = 0; j < 8; ++j) {
                const int k = kb * 8 + j;
                const float4 m = *(const float4*)&Ms[k][och];
                const float4 x = buf[kb & 1][j];
                acc[0][0] += m.x * x.x; acc[0][1] += m.x * x.y;
                acc[0][2] += m.x * x.z; acc[0][3] += m.x * x.w;
                acc[1][0] += m.y * x.x; acc[1][1] += m.y * x.y;
                acc[1][2] += m.y * x.z; acc[1][3] += m.y * x.w;
                acc[2][0] += m.z * x.x; acc[2][1] += m.z * x.y;
                acc[2][2] += m.z * x.z; acc[2][3] += m.z * x.w;
                acc[3][0] += m.w * x.x; acc[3][1] += m.w * x.y;
                acc[3][2] += m.w * x.z; acc[3][3] += m.w * x.w;
            }
        }

#pragma unroll
        for (int i = 0; i < 4; ++i) {
            const float bv = (i == 0) ? bias.x : (i == 1) ? bias.y
                           : (i == 2) ? bias.z : bias.w;
            float4 o4;
            o4.x = acc[i][0] + bv; o4.y = acc[i][1] + bv;
            o4.z = acc[i][2] + bv; o4.w = acc[i][3] + bv;
            *(float4*)&out[((size_t)b * CH + och + i) * NPIX + px] = o4;
        }
    }
}

// ---------------------------------------------------------------------------
extern "C" void kernel_launch(void* const* d_in, const int* in_sizes, int n_in,
                              void* d_out, int out_size, void* d_ws, size_t ws_size,
                              hipStream_t stream) {
    const float* tmap   = (const float*)d_in[0];
    const float* rmap   = (const float*)d_in[1];
    const float* gamma  = (const float*)d_in[2];
    const float* omega  = (const float*)d_in[3];
    const float* conv_w = (const float*)d_in[4];
    const float* conv_b = (const float*)d_in[5];
    float* out = (float*)d_out;

    // ws layout: G [16][2][4096] fp32 (512 KiB), then Mt [16][128][64] fp32 (512 KiB)
    float* G  = (float*)d_ws;
    float* Mt = (float*)((char*)d_ws + (size_t)BATCH * 2 * 4096 * sizeof(float));

    hipMemsetAsync(d_ws, 0, (size_t)BATCH * 2 * 4096 * sizeof(float), stream);

    gram_kernel<<<dim3(32, 2, BATCH), 256, 0, stream>>>(tmap, rmap, gamma, omega, G);
    finalize_kernel<<<dim3(BATCH), 128, 0, stream>>>(G, gamma, omega, conv_w, Mt);
    out_kernel<<<dim3(64, BATCH), 256, 0, stream>>>(tmap, rmap, Mt, conv_b, out);
}

// Round 3
// 219.717 us; speedup vs baseline: 3.5391x; 3.5391x over previous
//
#include <hip/hip_runtime.h>

#define BATCH 16
#define CH 64
#define NPIX 16384   // 128*128
#define TWOC 128

// ---------------------------------------------------------------------------
// Kernel 1: partial Gram matrices G[b][map][64][64] = sum_n V[c,n]*V[d,n]
// map 0 = template (feeds t_attn, used iff omega!=0)
// map 1 = roi      (feeds r_attn, used iff gamma!=0)
// Early-exits when the corresponding scalar is exactly 0 (contribution is
// exactly zero in that case -- algebraic short-circuit, still deterministic).
// ---------------------------------------------------------------------------
__global__ __launch_bounds__(256) void gram_kernel(
    const float* __restrict__ tmap, const float* __restrict__ rmap,
    const float* __restrict__ gamma, const float* __restrict__ omega,
    float* __restrict__ G)
{
    const int map = blockIdx.y;
    const float mult = (map == 0) ? omega[0] : gamma[0];
    if (mult == 0.f) return;   // wave-uniform: skip dead attention branch

    __shared__ float tile[64][68];
    const int chunk = blockIdx.x;    // 0..31 -> 512 cols each
    const int b     = blockIdx.z;
    const float* x = (map == 0 ? tmap : rmap) + (size_t)b * CH * NPIX + chunk * 512;
    const int t  = threadIdx.x;
    const int ti = t >> 4;
    const int tj = t & 15;

    float acc[4][4];
#pragma unroll
    for (int i = 0; i < 4; ++i)
#pragma unroll
        for (int j = 0; j < 4; ++j) acc[i][j] = 0.f;

    for (int tt = 0; tt < 8; ++tt) {
        const int col0 = tt * 64;
#pragma unroll
        for (int k = 0; k < 16; ++k) {
            int e = t + 256 * k;
            int c = e >> 6, col = e & 63;
            tile[c][col] = x[(size_t)c * NPIX + col0 + col];
        }
        __syncthreads();
#pragma unroll 8
        for (int n = 0; n < 64; n += 2) {
            float2 av[4], bv[4];
#pragma unroll
            for (int i = 0; i < 4; ++i) av[i] = *(const float2*)&tile[ti + 16 * i][n];
#pragma unroll
            for (int j = 0; j < 4; ++j) bv[j] = *(const float2*)&tile[tj + 16 * j][n];
#pragma unroll
            for (int i = 0; i < 4; ++i)
#pragma unroll
                for (int j = 0; j < 4; ++j) {
                    acc[i][j] += av[i].x * bv[j].x;
                    acc[i][j] += av[i].y * bv[j].y;
                }
        }
        __syncthreads();
    }
    float* Gp = G + ((size_t)(b * 2 + map) << 12);
#pragma unroll
    for (int i = 0; i < 4; ++i)
#pragma unroll
        for (int j = 0; j < 4; ++j)
            atomicAdd(&Gp[(ti + 16 * i) * 64 + (tj + 16 * j)], acc[i][j]);
}

// ---------------------------------------------------------------------------
// Kernel 2: per-batch softmax + build TRANSPOSED mixing matrix
//   Mt[b][k][o] = conv_w[o][k] + (k<64 ? gamma*(W1@r_attn)[o][k]
//                                       : omega*(W2@t_attn)[o][k-64])
// ---------------------------------------------------------------------------
__global__ __launch_bounds__(128) void finalize_kernel(
    const float* __restrict__ G, const float* __restrict__ gamma,
    const float* __restrict__ omega, const float* __restrict__ conv_w,
    float* __restrict__ Mt)
{
    __shared__ float attn[2][64][64];
    const int b = blockIdx.x;
    const int t = threadIdx.x;
    const float gam = gamma[0], om = omega[0];
    {
        const int map = t >> 6, i = t & 63;
        const float need = (map == 0) ? om : gam;
        if (need != 0.f) {
            const float* Grow = G + ((size_t)(b * 2 + map) << 12) + i * 64;
            float mn = Grow[0];
            for (int j = 1; j < 64; ++j) mn = fminf(mn, Grow[j]);
            float s = 0.f;
            for (int j = 0; j < 64; ++j) s += expf(mn - Grow[j]);
            const float inv = 1.f / s;
            for (int j = 0; j < 64; ++j) attn[map][i][j] = expf(mn - Grow[j]) * inv;
        }
    }
    __syncthreads();
    for (int idx = t; idx < CH * TWOC; idx += 128) {
        const int k = idx >> 6, o = idx & 63;       // Mt layout [128 k][64 o]
        const float* wrow = conv_w + o * TWOC;
        float v;
        if (k < 64) {
            v = wrow[k];
            if (gam != 0.f) {
                float dot = 0.f;
                for (int c = 0; c < 64; ++c) dot += wrow[c] * attn[1][c][k];      // r_attn
                v += gam * dot;
            }
        } else {
            const int d = k - 64;
            v = wrow[k];
            if (om != 0.f) {
                float dot = 0.f;
                for (int c = 0; c < 64; ++c) dot += wrow[64 + c] * attn[0][c][d]; // t_attn
                v += om * dot;
            }
        }
        Mt[(size_t)b * (CH * TWOC) + idx] = v;
    }
}

// ---------------------------------------------------------------------------
// Kernel 3: out[b][o][n] = sum_k Mt[b][k][o] * X[k][n] + conv_b[o]
// X rows 0..63 = template channels, 64..127 = roi channels.
//
// Block 256 = 4 waves. Wave w -> output channels [16w,16w+16).
// Lane l -> one float4 of pixels at px = blockIdx.x*256 + l*4, so each
// wave's global X load per k is one perfectly-coalesced 1 KB row (the 4x
// cross-wave reuse of the same row is served by L1, not HBM).
// M is LDS-broadcast (lane-uniform ds_read_b128 -> no bank pressure).
// Inner loop per k: 1 global float4 + 4 broadcast b128 + 64 FMAs.
// X prefetch ring depth 4 with static indices (unroll-4).
// __launch_bounds__(256,4): cap VGPR at 128 -> 4 blocks/CU (grid = 1024
// blocks = exactly 4 per CU).
// ---------------------------------------------------------------------------
__global__ __launch_bounds__(256, 4) void out_kernel(
    const float* __restrict__ tmap, const float* __restrict__ rmap,
    const float* __restrict__ Mt, const float* __restrict__ conv_b,
    float* __restrict__ out)
{
    __shared__ float Ms[128][64];     // 32 KB, [k][och]
    const int b = blockIdx.y;
    const int t = threadIdx.x;

    {
        const float4* src = (const float4*)(Mt + (size_t)b * (CH * TWOC));
        float4* dst = (float4*)&Ms[0][0];
#pragma unroll
        for (int i = 0; i < 8; ++i) dst[t + 256 * i] = src[t + 256 * i];
    }
    __syncthreads();

    const int w    = t >> 6;          // wave id -> och group
    const int l    = t & 63;
    const int px   = blockIdx.x * 256 + l * 4;
    const int och0 = w * 16;

    const float* xt = tmap + (size_t)b * CH * NPIX + px;   // rows 0..63
    const float* xr = rmap + (size_t)b * CH * NPIX + px;   // rows 64..127

    float4 acc[16];
#pragma unroll
    for (int o = 0; o < 16; ++o) acc[o] = make_float4(0.f, 0.f, 0.f, 0.f);

    // prefetch ring, depth 4 (k=0..3 are template rows)
    float4 xb[4];
#pragma unroll
    for (int i = 0; i < 4; ++i) xb[i] = *(const float4*)&xt[(size_t)i * NPIX];

    for (int k4 = 0; k4 < 128; k4 += 4) {
#pragma unroll
        for (int u = 0; u < 4; ++u) {
            const int k = k4 + u;
            const float4 x = xb[u];
            const int kn = k + 4;
            if (kn < 128) {
                const float* src = (kn < 64) ? &xt[(size_t)kn * NPIX]
                                             : &xr[(size_t)(kn - 64) * NPIX];
                xb[u] = *(const float4*)src;
            }
#pragma unroll
            for (int og = 0; og < 4; ++og) {
                const float4 m = *(const float4*)&Ms[k][och0 + og * 4];
                acc[og * 4 + 0].x += m.x * x.x; acc[og * 4 + 0].y += m.x * x.y;
                acc[og * 4 + 0].z += m.x * x.z; acc[og * 4 + 0].w += m.x * x.w;
                acc[og * 4 + 1].x += m.y * x.x; acc[og * 4 + 1].y += m.y * x.y;
                acc[og * 4 + 1].z += m.y * x.z; acc[og * 4 + 1].w += m.y * x.w;
                acc[og * 4 + 2].x += m.z * x.x; acc[og * 4 + 2].y += m.z * x.y;
                acc[og * 4 + 2].z += m.z * x.z; acc[og * 4 + 2].w += m.z * x.w;
                acc[og * 4 + 3].x += m.w * x.x; acc[og * 4 + 3].y += m.w * x.y;
                acc[og * 4 + 3].z += m.w * x.z; acc[og * 4 + 3].w += m.w * x.w;
            }
        }
    }

#pragma unroll
    for (int o = 0; o < 16; ++o) {
        const float bv = conv_b[och0 + o];      // wave-uniform scalar load
        float4 o4;
        o4.x = acc[o].x + bv; o4.y = acc[o].y + bv;
        o4.z = acc[o].z + bv; o4.w = acc[o].w + bv;
        *(float4*)&out[((size_t)b * CH + och0 + o) * NPIX + px] = o4;
    }
}

// ---------------------------------------------------------------------------
extern "C" void kernel_launch(void* const* d_in, const int* in_sizes, int n_in,
                              void* d_out, int out_size, void* d_ws, size_t ws_size,
                              hipStream_t stream) {
    const float* tmap   = (const float*)d_in[0];
    const float* rmap   = (const float*)d_in[1];
    const float* gamma  = (const float*)d_in[2];
    const float* omega  = (const float*)d_in[3];
    const float* conv_w = (const float*)d_in[4];
    const float* conv_b = (const float*)d_in[5];
    float* out = (float*)d_out;

    // ws layout: G [16][2][4096] fp32 (512 KiB), then Mt [16][128][64] fp32 (512 KiB)
    float* G  = (float*)d_ws;
    float* Mt = (float*)((char*)d_ws + (size_t)BATCH * 2 * 4096 * sizeof(float));

    hipMemsetAsync(d_ws, 0, (size_t)BATCH * 2 * 4096 * sizeof(float), stream);

    gram_kernel<<<dim3(32, 2, BATCH), 256, 0, stream>>>(tmap, rmap, gamma, omega, G);
    finalize_kernel<<<dim3(BATCH), 128, 0, stream>>>(G, gamma, omega, conv_w, Mt);
    out_kernel<<<dim3(64, BATCH), 256, 0, stream>>>(tmap, rmap, Mt, conv_b, out);
}

// Round 4
// 55.399 us; speedup vs baseline: 14.0364x; 3.9661x over previous
//
#include <hip/hip_runtime.h>

typedef __attribute__((ext_vector_type(8))) short short8;
typedef __attribute__((ext_vector_type(4))) float floatx4;
typedef unsigned int uint;
typedef unsigned short ushort;

#define BATCH 16
#define CH 64
#define NPIX 16384   // 128*128
#define TWOC 128

__device__ __forceinline__ ushort f2bf(float f) {   // RNE f32 -> bf16 bits
    uint u = __float_as_uint(f);
    u += 0x7FFFu + ((u >> 16) & 1u);
    return (ushort)(u >> 16);
}

// ---------------------------------------------------------------------------
// Kernel 1: partial Gram matrices G[b][map][64][64] = sum_n V[c,n]*V[d,n]
// map 0 = template (feeds t_attn, used iff omega!=0)
// map 1 = roi      (feeds r_attn, used iff gamma!=0)
// Early-exits when the corresponding scalar is exactly 0 (contribution is
// exactly zero in that case -- algebraic short-circuit, still deterministic).
// ---------------------------------------------------------------------------
__global__ __launch_bounds__(256) void gram_kernel(
    const float* __restrict__ tmap, const float* __restrict__ rmap,
    const float* __restrict__ gamma, const float* __restrict__ omega,
    float* __restrict__ G)
{
    const int map = blockIdx.y;
    const float mult = (map == 0) ? omega[0] : gamma[0];
    if (mult == 0.f) return;   // wave-uniform: skip dead attention branch

    __shared__ float tile[64][68];
    const int chunk = blockIdx.x;
    const int b     = blockIdx.z;
    const float* x = (map == 0 ? tmap : rmap) + (size_t)b * CH * NPIX + chunk * 512;
    const int t  = threadIdx.x;
    const int ti = t >> 4;
    const int tj = t & 15;

    float acc[4][4];
#pragma unroll
    for (int i = 0; i < 4; ++i)
#pragma unroll
        for (int j = 0; j < 4; ++j) acc[i][j] = 0.f;

    for (int tt = 0; tt < 8; ++tt) {
        const int col0 = tt * 64;
#pragma unroll
        for (int k = 0; k < 16; ++k) {
            int e = t + 256 * k;
            int c = e >> 6, col = e & 63;
            tile[c][col] = x[(size_t)c * NPIX + col0 + col];
        }
        __syncthreads();
#pragma unroll 8
        for (int n = 0; n < 64; n += 2) {
            float2 av[4], bv[4];
#pragma unroll
            for (int i = 0; i < 4; ++i) av[i] = *(const float2*)&tile[ti + 16 * i][n];
#pragma unroll
            for (int j = 0; j < 4; ++j) bv[j] = *(const float2*)&tile[tj + 16 * j][n];
#pragma unroll
            for (int i = 0; i < 4; ++i)
#pragma unroll
                for (int j = 0; j < 4; ++j) {
                    acc[i][j] += av[i].x * bv[j].x;
                    acc[i][j] += av[i].y * bv[j].y;
                }
        }
        __syncthreads();
    }
    float* Gp = G + ((size_t)(b * 2 + map) << 12);
#pragma unroll
    for (int i = 0; i < 4; ++i)
#pragma unroll
        for (int j = 0; j < 4; ++j)
            atomicAdd(&Gp[(ti + 16 * i) * 64 + (tj + 16 * j)], acc[i][j]);
}

// ---------------------------------------------------------------------------
// Kernel 2: per-batch softmax + build mixing matrix, stored as bf16
// A-FRAGMENTS for mfma_f32_16x16x32_bf16:
//   flat idx = ((kstep*4 + mi)*64 + lane)*8 + e
//   holds M[mi*16 + (lane&15)][kstep*32 + (lane>>4)*8 + e]
// where M[o][k] = conv_w[o][k] + (k<64 ? gamma*(W1@r_attn)[o][k]
//                                      : omega*(W2@t_attn)[o][k-64])
// ---------------------------------------------------------------------------
__global__ __launch_bounds__(128) void finalize_kernel(
    const float* __restrict__ G, const float* __restrict__ gamma,
    const float* __restrict__ omega, const float* __restrict__ conv_w,
    ushort* __restrict__ Mtf)
{
    __shared__ float attn[2][64][64];
    const int b = blockIdx.x;
    const int t = threadIdx.x;
    const float gam = gamma[0], om = omega[0];
    {
        const int map = t >> 6, i = t & 63;
        const float need = (map == 0) ? om : gam;
        if (need != 0.f) {
            const float* Grow = G + ((size_t)(b * 2 + map) << 12) + i * 64;
            float mn = Grow[0];
            for (int j = 1; j < 64; ++j) mn = fminf(mn, Grow[j]);
            float s = 0.f;
            for (int j = 0; j < 64; ++j) s += expf(mn - Grow[j]);
            const float inv = 1.f / s;
            for (int j = 0; j < 64; ++j) attn[map][i][j] = expf(mn - Grow[j]) * inv;
        }
    }
    __syncthreads();
    for (int idx = t; idx < 8192; idx += 128) {
        const int e     = idx & 7;
        const int l     = (idx >> 3) & 63;
        const int mi    = (idx >> 9) & 3;
        const int kstep = idx >> 11;
        const int row = mi * 16 + (l & 15);
        const int k   = kstep * 32 + (l >> 4) * 8 + e;
        const float* wrow = conv_w + row * TWOC;
        float v = wrow[k];
        if (k < 64) {
            if (gam != 0.f) {
                float dot = 0.f;
                for (int c = 0; c < 64; ++c) dot += wrow[c] * attn[1][c][k];      // r_attn
                v += gam * dot;
            }
        } else {
            const int d = k - 64;
            if (om != 0.f) {
                float dot = 0.f;
                for (int c = 0; c < 64; ++c) dot += wrow[64 + c] * attn[0][c][d]; // t_attn
                v += om * dot;
            }
        }
        Mtf[(size_t)b * 8192 + idx] = f2bf(v);
    }
}

// ---------------------------------------------------------------------------
// Kernel 3 (MFMA): out[b](64 x 16384) = M[b](64x128) @ X(128x16384) + bias
// X rows 0..63 = template channels, 64..127 = roi channels.
// Block 256 thr = 4 waves, tile = 64 och x 256 px; wave w -> px [64w,64w+64).
// K processed in two 64-row halves (exactly template rows then roi rows):
//   stage: thread t owns px0+t; loads 8-k columns (each global read is a
//          full-wave 256B coalesced row read), converts to bf16, one
//          ds_write_b128 into Xs[i][px][e] (i = k-octet, e = k&7).
//   compute: per k-step (K=32): 4 A-frags (ds_read_b128 from Ms, uniform
//          addresses) x 4 B-frags -> 16 mfma_f32_16x16x32_bf16, f32 accum.
// LDS = 16KB (Ms) + 32KB (Xs) = 48KB -> 3 blocks/CU.
// ---------------------------------------------------------------------------
__global__ __launch_bounds__(256, 3) void out_kernel(
    const float* __restrict__ tmap, const float* __restrict__ rmap,
    const ushort* __restrict__ Mtf, const float* __restrict__ conv_b,
    float* __restrict__ out)
{
    __shared__ __align__(16) ushort Ms[8192];          // 16 KB: A fragments
    __shared__ __align__(16) ushort Xs[8 * 256 * 8];   // 32 KB: B half-tile

    const int b   = blockIdx.y;
    const int t   = threadIdx.x;
    const int px0 = blockIdx.x * 256;

    // stage M fragments -> LDS (coalesced uint4 copy)
    {
        const uint4* src = (const uint4*)(Mtf + (size_t)b * 8192);
        uint4* dst = (uint4*)Ms;
#pragma unroll
        for (int i = 0; i < 4; ++i) dst[t + 256 * i] = src[t + 256 * i];
    }

    const int w  = t >> 6;        // wave -> px quadrant
    const int l  = t & 63;
    const int lg = l >> 4;        // k-group / C row-group
    const int lj = l & 15;        // C col / A row / B col within tile

    const float* xsrc0 = tmap + (size_t)b * CH * NPIX + px0 + t;
    const float* xsrc1 = rmap + (size_t)b * CH * NPIX + px0 + t;

    floatx4 acc[4][4];
#pragma unroll
    for (int mi = 0; mi < 4; ++mi)
#pragma unroll
        for (int nj = 0; nj < 4; ++nj) acc[mi][nj] = (floatx4){0.f, 0.f, 0.f, 0.f};

    float bias[4][4];
#pragma unroll
    for (int mi = 0; mi < 4; ++mi)
#pragma unroll
        for (int r = 0; r < 4; ++r) bias[mi][r] = conv_b[mi * 16 + lg * 4 + r];

#pragma unroll
    for (int h = 0; h < 2; ++h) {
        const float* s = (h == 0) ? xsrc0 : xsrc1;
        // stage X half-tile: 8 k-octets
#pragma unroll
        for (int i = 0; i < 8; ++i) {
            float v[8];
#pragma unroll
            for (int e = 0; e < 8; ++e) v[e] = s[(size_t)(i * 8 + e) * NPIX];
            short8 pk;
#pragma unroll
            for (int e = 0; e < 8; ++e) pk[e] = (short)f2bf(v[e]);
            *(short8*)&Xs[(i * 256 + t) * 8] = pk;
        }
        __syncthreads();   // Xs (and, h==0, Ms) ready

#pragma unroll
        for (int ks = 0; ks < 2; ++ks) {
            short8 a[4];
#pragma unroll
            for (int mi = 0; mi < 4; ++mi)
                a[mi] = *(const short8*)&Ms[(((h * 2 + ks) * 4 + mi) * 64 + l) * 8];
#pragma unroll
            for (int nj = 0; nj < 4; ++nj) {
                const short8 bb = *(const short8*)
                    &Xs[((ks * 4 + lg) * 256 + w * 64 + nj * 16 + lj) * 8];
#pragma unroll
                for (int mi = 0; mi < 4; ++mi)
                    acc[mi][nj] = __builtin_amdgcn_mfma_f32_16x16x32_bf16(
                        a[mi], bb, acc[mi][nj], 0, 0, 0);
            }
        }
        __syncthreads();   // done reading Xs before overwrite
    }

    // epilogue: C/D layout col=lane&15, row=(lane>>4)*4+reg (guide m89/m91)
#pragma unroll
    for (int mi = 0; mi < 4; ++mi)
#pragma unroll
        for (int nj = 0; nj < 4; ++nj) {
            const int px = px0 + w * 64 + nj * 16 + lj;
#pragma unroll
            for (int r = 0; r < 4; ++r) {
                const int och = mi * 16 + lg * 4 + r;
                out[((size_t)b * CH + och) * NPIX + px] = acc[mi][nj][r] + bias[mi][r];
            }
        }
}

// ---------------------------------------------------------------------------
extern "C" void kernel_launch(void* const* d_in, const int* in_sizes, int n_in,
                              void* d_out, int out_size, void* d_ws, size_t ws_size,
                              hipStream_t stream) {
    const float* tmap   = (const float*)d_in[0];
    const float* rmap   = (const float*)d_in[1];
    const float* gamma  = (const float*)d_in[2];
    const float* omega  = (const float*)d_in[3];
    const float* conv_w = (const float*)d_in[4];
    const float* conv_b = (const float*)d_in[5];
    float* out = (float*)d_out;

    // ws layout: G [16][2][4096] fp32 (512 KiB), then Mtf [16][8192] bf16 (256 KiB)
    float*  G   = (float*)d_ws;
    ushort* Mtf = (ushort*)((char*)d_ws + (size_t)BATCH * 2 * 4096 * sizeof(float));

    hipMemsetAsync(d_ws, 0, (size_t)BATCH * 2 * 4096 * sizeof(float), stream);

    gram_kernel<<<dim3(32, 2, BATCH), 256, 0, stream>>>(tmap, rmap, gamma, omega, G);
    finalize_kernel<<<dim3(BATCH), 128, 0, stream>>>(G, gamma, omega, conv_w, Mtf);
    out_kernel<<<dim3(64, BATCH), 256, 0, stream>>>(tmap, rmap, Mtf, conv_b, out);
}

// Round 5
// 53.523 us; speedup vs baseline: 14.5283x; 1.0350x over previous
//
#include <hip/hip_runtime.h>

typedef __attribute__((ext_vector_type(8))) short short8;
typedef __attribute__((ext_vector_type(4))) float floatx4;
typedef unsigned int uint;
typedef unsigned short ushort;

#define BATCH 16
#define CH 64
#define NPIX 16384   // 128*128
#define TWOC 128

__device__ __forceinline__ ushort f2bf(float f) {   // RNE f32 -> bf16 bits
    uint u = __float_as_uint(f);
    u += 0x7FFFu + ((u >> 16) & 1u);
    return (ushort)(u >> 16);
}

// ---------------------------------------------------------------------------
// Kernel 1: partial Gram matrices G[b][map][64][64] = sum_n V[c,n]*V[d,n]
// map 0 = template (feeds t_attn, used iff omega!=0)
// map 1 = roi      (feeds r_attn, used iff gamma!=0)
// Early-exits when the corresponding scalar is exactly 0 (contribution is
// exactly zero in that case -- algebraic short-circuit, still deterministic).
// ---------------------------------------------------------------------------
__global__ __launch_bounds__(256) void gram_kernel(
    const float* __restrict__ tmap, const float* __restrict__ rmap,
    const float* __restrict__ gamma, const float* __restrict__ omega,
    float* __restrict__ G)
{
    const int map = blockIdx.y;
    const float mult = (map == 0) ? omega[0] : gamma[0];
    if (mult == 0.f) return;   // wave-uniform: skip dead attention branch

    __shared__ float tile[64][68];
    const int chunk = blockIdx.x;
    const int b     = blockIdx.z;
    const float* x = (map == 0 ? tmap : rmap) + (size_t)b * CH * NPIX + chunk * 512;
    const int t  = threadIdx.x;
    const int ti = t >> 4;
    const int tj = t & 15;

    float acc[4][4];
#pragma unroll
    for (int i = 0; i < 4; ++i)
#pragma unroll
        for (int j = 0; j < 4; ++j) acc[i][j] = 0.f;

    for (int tt = 0; tt < 8; ++tt) {
        const int col0 = tt * 64;
#pragma unroll
        for (int k = 0; k < 16; ++k) {
            int e = t + 256 * k;
            int c = e >> 6, col = e & 63;
            tile[c][col] = x[(size_t)c * NPIX + col0 + col];
        }
        __syncthreads();
#pragma unroll 8
        for (int n = 0; n < 64; n += 2) {
            float2 av[4], bv[4];
#pragma unroll
            for (int i = 0; i < 4; ++i) av[i] = *(const float2*)&tile[ti + 16 * i][n];
#pragma unroll
            for (int j = 0; j < 4; ++j) bv[j] = *(const float2*)&tile[tj + 16 * j][n];
#pragma unroll
            for (int i = 0; i < 4; ++i)
#pragma unroll
                for (int j = 0; j < 4; ++j) {
                    acc[i][j] += av[i].x * bv[j].x;
                    acc[i][j] += av[i].y * bv[j].y;
                }
        }
        __syncthreads();
    }
    float* Gp = G + ((size_t)(b * 2 + map) << 12);
#pragma unroll
    for (int i = 0; i < 4; ++i)
#pragma unroll
        for (int j = 0; j < 4; ++j)
            atomicAdd(&Gp[(ti + 16 * i) * 64 + (tj + 16 * j)], acc[i][j]);
}

// ---------------------------------------------------------------------------
// Kernel 2: per-batch softmax + build mixing matrix, stored as bf16
// A-FRAGMENTS for mfma_f32_16x16x32_bf16:
//   flat idx = ((kstep*4 + mi)*64 + lane)*8 + e
//   holds M[mi*16 + (lane&15)][kstep*32 + (lane>>4)*8 + e]
// where M[o][k] = conv_w[o][k] + (k<64 ? gamma*(W1@r_attn)[o][k]
//                                      : omega*(W2@t_attn)[o][k-64])
// ---------------------------------------------------------------------------
__global__ __launch_bounds__(128) void finalize_kernel(
    const float* __restrict__ G, const float* __restrict__ gamma,
    const float* __restrict__ omega, const float* __restrict__ conv_w,
    ushort* __restrict__ Mtf)
{
    __shared__ float attn[2][64][64];
    const int b = blockIdx.x;
    const int t = threadIdx.x;
    const float gam = gamma[0], om = omega[0];
    {
        const int map = t >> 6, i = t & 63;
        const float need = (map == 0) ? om : gam;
        if (need != 0.f) {
            const float* Grow = G + ((size_t)(b * 2 + map) << 12) + i * 64;
            float mn = Grow[0];
            for (int j = 1; j < 64; ++j) mn = fminf(mn, Grow[j]);
            float s = 0.f;
            for (int j = 0; j < 64; ++j) s += expf(mn - Grow[j]);
            const float inv = 1.f / s;
            for (int j = 0; j < 64; ++j) attn[map][i][j] = expf(mn - Grow[j]) * inv;
        }
    }
    __syncthreads();
    for (int idx = t; idx < 8192; idx += 128) {
        const int e     = idx & 7;
        const int l     = (idx >> 3) & 63;
        const int mi    = (idx >> 9) & 3;
        const int kstep = idx >> 11;
        const int row = mi * 16 + (l & 15);
        const int k   = kstep * 32 + (l >> 4) * 8 + e;
        const float* wrow = conv_w + row * TWOC;
        float v = wrow[k];
        if (k < 64) {
            if (gam != 0.f) {
                float dot = 0.f;
                for (int c = 0; c < 64; ++c) dot += wrow[c] * attn[1][c][k];      // r_attn
                v += gam * dot;
            }
        } else {
            const int d = k - 64;
            if (om != 0.f) {
                float dot = 0.f;
                for (int c = 0; c < 64; ++c) dot += wrow[64 + c] * attn[0][c][d]; // t_attn
                v += om * dot;
            }
        }
        Mtf[(size_t)b * 8192 + idx] = f2bf(v);
    }
}

// ---------------------------------------------------------------------------
// Kernel 3 (MFMA, zero-LDS, zero-barrier):
//   out[b](64 x 16384) = M[b](64x128) @ X(128x16384) + bias
// X rows 0..63 = template channels, 64..127 = roi channels.
//
// Block 256 thr = 4 waves; wave w owns px quadrant [px0+64w, px0+64w+64) for
// ALL 64 output channels -> zero cross-wave data sharing -> no LDS needed.
//   A-frags: direct per-wave contiguous 1KB dwordx4 reads of Mtf (already
//            fragment-ordered; L2/L3-resident, shared by all 64 px-blocks).
//   B-frags: lane l loads its 8 k-strided scalars (per wave-instruction:
//            4 x 64B coalesced segments, all bytes used), converts to bf16
//            in-register, packs short8. Same HBM bytes as LDS staging, but
//            no ds_write/ds_read round-trip and no __syncthreads -- waves
//            free-run and the compiler overlaps loads under MFMAs.
// Grid 64x16 = 1024 blocks x 4 waves = 4096 waves = exactly one full
// residency round at 16 waves/CU (VGPR-bound, no tail).
// ---------------------------------------------------------------------------
__global__ __launch_bounds__(256, 3) void out_kernel(
    const float* __restrict__ tmap, const float* __restrict__ rmap,
    const ushort* __restrict__ Mtf, const float* __restrict__ conv_b,
    float* __restrict__ out)
{
    const int b   = blockIdx.y;
    const int t   = threadIdx.x;
    const int w   = t >> 6;        // wave -> px quadrant
    const int l   = t & 63;
    const int lg  = l >> 4;        // k-octet group / C row-group
    const int lj  = l & 15;        // B col / C col within 16x16 tile
    const int pxw = blockIdx.x * 256 + w * 64;

    const ushort* mbase = Mtf + (size_t)b * 8192;

    floatx4 acc[4][4];             // [mi][nj]
#pragma unroll
    for (int mi = 0; mi < 4; ++mi)
#pragma unroll
        for (int nj = 0; nj < 4; ++nj) acc[mi][nj] = (floatx4){0.f, 0.f, 0.f, 0.f};

#pragma unroll
    for (int h = 0; h < 2; ++h) {
        const float* src = ((h == 0) ? tmap : rmap) + (size_t)b * CH * NPIX;
#pragma unroll
        for (int ks = 0; ks < 2; ++ks) {
            // A-fragments: 4 x 16B contiguous per lane
            short8 a[4];
#pragma unroll
            for (int mi = 0; mi < 4; ++mi)
                a[mi] = *(const short8*)&mbase[((((h * 2 + ks) * 4 + mi) * 64) + l) * 8];

#pragma unroll
            for (int nj = 0; nj < 4; ++nj) {
                // B-fragment: 8 k-strided scalars for this lane's (k-octet, px)
                const float* cbase = src + (size_t)(ks * 32 + lg * 8) * NPIX
                                         + pxw + nj * 16 + lj;
                float v[8];
#pragma unroll
                for (int e = 0; e < 8; ++e) v[e] = cbase[(size_t)e * NPIX];
                short8 bb;
#pragma unroll
                for (int e = 0; e < 8; ++e) bb[e] = (short)f2bf(v[e]);
#pragma unroll
                for (int mi = 0; mi < 4; ++mi)
                    acc[mi][nj] = __builtin_amdgcn_mfma_f32_16x16x32_bf16(
                        a[mi], bb, acc[mi][nj], 0, 0, 0);
            }
        }
    }

    // epilogue: C/D layout col=lane&15, row=(lane>>4)*4+reg (guide m89/m91)
#pragma unroll
    for (int mi = 0; mi < 4; ++mi) {
#pragma unroll
        for (int r = 0; r < 4; ++r) {
            const int och = mi * 16 + lg * 4 + r;
            const float bv = conv_b[och];
            float* orow = out + ((size_t)b * CH + och) * NPIX;
#pragma unroll
            for (int nj = 0; nj < 4; ++nj)
                orow[pxw + nj * 16 + lj] = acc[mi][nj][r] + bv;
        }
    }
}

// ---------------------------------------------------------------------------
extern "C" void kernel_launch(void* const* d_in, const int* in_sizes, int n_in,
                              void* d_out, int out_size, void* d_ws, size_t ws_size,
                              hipStream_t stream) {
    const float* tmap   = (const float*)d_in[0];
    const float* rmap   = (const float*)d_in[1];
    const float* gamma  = (const float*)d_in[2];
    const float* omega  = (const float*)d_in[3];
    const float* conv_w = (const float*)d_in[4];
    const float* conv_b = (const float*)d_in[5];
    float* out = (float*)d_out;

    // ws layout: G [16][2][4096] fp32 (512 KiB), then Mtf [16][8192] bf16 (256 KiB)
    float*  G   = (float*)d_ws;
    ushort* Mtf = (ushort*)((char*)d_ws + (size_t)BATCH * 2 * 4096 * sizeof(float));

    hipMemsetAsync(d_ws, 0, (size_t)BATCH * 2 * 4096 * sizeof(float), stream);

    gram_kernel<<<dim3(32, 2, BATCH), 256, 0, stream>>>(tmap, rmap, gamma, omega, G);
    finalize_kernel<<<dim3(BATCH), 128, 0, stream>>>(G, gamma, omega, conv_w, Mtf);
    out_kernel<<<dim3(64, BATCH), 256, 0, stream>>>(tmap, rmap, Mtf, conv_b, out);
}